// Round 5
// baseline (4997.908 us; speedup 1.0000x reference)
//
#include <hip/hip_runtime.h>
#include <hip/hip_bf16.h>
#include <stdint.h>

// GatedGNN: B=256, N=80, D=1024, T=3
#define B_   256
#define N_   80
#define D_   1024
#define M_   (B_*N_)     // 20480 rows (b*80+node)
// Abuf row (bf16), SA_=8192: [a_hi(0:2048)|a_lo(2048:4096)|h_hi(4096:5120)|h_lo(5120:6144)|rh_hi(6144:7168)|rh_lo(7168:8192)]
#define SA_  8192
// W row (bf16), SW_=6144: [w_a_hi(0:2048)|w_a_lo(2048:4096)|w_u_hi(4096:5120)|w_u_lo(5120:6144)]
#define SW_  6144
// Combined-plane staging at BK=32. 96 chunks: [0,64) a-part (K=2048), [64,96) u-part (K=1024).
#define KT_  96

typedef __attribute__((ext_vector_type(8))) short bf16x8;   // 8 bf16 = 4 VGPRs
typedef __attribute__((ext_vector_type(4))) float f32x4;

__device__ __forceinline__ void async_cp16(const void* g, void* l) {
  __builtin_amdgcn_global_load_lds((const __attribute__((address_space(1))) unsigned int*)g,
                                   (__attribute__((address_space(3))) unsigned int*)l,
                                   16, 0, 0);
}
__device__ __forceinline__ float sigm_(float x) { return 1.0f / (1.0f + __expf(-x)); }
__device__ __forceinline__ float tanh_(float x) { return 2.0f / (1.0f + __expf(-2.0f * x)) - 1.0f; }
__device__ __forceinline__ void split_bf16(float v, __hip_bfloat16& hi, __hip_bfloat16& lo) {
  hi = __float2bfloat16(v);
  lo = __float2bfloat16(v - __bfloat162float(hi));
}
__device__ __forceinline__ void plane_offsets(int kt, int UBASE, int& ahi, int& alo, int& whi, int& wlo) {
  if (kt < 64) { const int c = kt * 32;        ahi = c;         alo = 2048 + c;
                 whi = c;                      wlo = 2048 + c; }
  else         { const int r = (kt - 64) * 32; ahi = UBASE + r; alo = UBASE + 1024 + r;
                 whi = 4096 + r;               wlo = 5120 + r; }
}

// ---------------- weight packing (hi/lo split): Wzr[2048][SW_], Wh[1024][SW_] ------------------
__global__ __launch_bounds__(256) void pack_weights(
    const float* __restrict__ W1w, const float* __restrict__ W1u,
    const float* __restrict__ W2w, const float* __restrict__ W2u,
    const float* __restrict__ W3w, const float* __restrict__ W3u,
    __hip_bfloat16* __restrict__ Wzr, __hip_bfloat16* __restrict__ Wh) {
  int idx = blockIdx.x * 256 + threadIdx.x;     // [0, 3072*3072)
  int n = idx / 3072, k = idx - n * 3072;       // n: 0..3071 output row, k: source col
  const float *Ww, *Wu; int nr; __hip_bfloat16* outrow;
  if (n < 1024)      { Ww = W1w; Wu = W1u; nr = n;        outrow = Wzr + (size_t)n * SW_; }
  else if (n < 2048) { Ww = W2w; Wu = W2u; nr = n - 1024; outrow = Wzr + (size_t)n * SW_; }
  else               { Ww = W3w; Wu = W3u; nr = n - 2048; outrow = Wh + (size_t)(n - 2048) * SW_; }
  float v; int chi, clo;
  if (k < 2048) { v = Ww[nr * 2048 + k];          chi = k;               clo = 2048 + k; }
  else          { v = Wu[nr * 1024 + (k - 2048)]; chi = 4096 + (k-2048); clo = 5120 + (k - 2048); }
  __hip_bfloat16 hi, lo; split_bf16(v, hi, lo);
  outrow[chi] = hi; outrow[clo] = lo;
}

// ---------------- propagation: a_in/a_out = inM/outM @ h[b] (fp32), split -> Abuf --------------
__global__ __launch_bounds__(256) void prop_kernel(
    const float* __restrict__ h, const float* __restrict__ inM,
    const float* __restrict__ outM, __hip_bfloat16* __restrict__ Abuf) {
  const int b = blockIdx.x;                        // chunk-local batch index
  const int d = blockIdx.y * 256 + threadIdx.x;
  const float* hb = h + (size_t)b * N_ * D_ + d;
  float hreg[N_];
  #pragma unroll
  for (int m = 0; m < N_; ++m) hreg[m] = hb[m * D_];
  __hip_bfloat16* Ab = Abuf + (size_t)b * N_ * SA_;
  #pragma unroll
  for (int m = 0; m < N_; ++m) {
    __hip_bfloat16 hi, lo; split_bf16(hreg[m], hi, lo);
    Ab[m * SA_ + 4096 + d] = hi; Ab[m * SA_ + 5120 + d] = lo;
  }
  for (int n = 0; n < N_; ++n) {
    float ai = 0.f, ao = 0.f;
    #pragma unroll
    for (int m = 0; m < N_; ++m) {
      ai += inM[n * N_ + m] * hreg[m];
      ao += outM[n * N_ + m] * hreg[m];
    }
    __hip_bfloat16 hi, lo;
    split_bf16(ai, hi, lo); Ab[n * SA_ + d] = hi;        Ab[n * SA_ + 2048 + d] = lo;
    split_bf16(ao, hi, lo); Ab[n * SA_ + 1024 + d] = hi; Ab[n * SA_ + 3072 + d] = lo;
  }
}

// ---------------- MFMA GEMM, 160x128 tile, BK=32 x 4 planes, 3-term split-bf16 ----------------
// wave-grid 2x2, wave-tile 80m x 64n, acc 5x4 (80 AGPR).
// R5: T3+T4 counted-vmcnt double-buffer pipeline (72 KB LDS, 2 blocks/CU).
//   R4 post-mortem: drain-every-iter structures sustain only ~21 B/cyc/CU of global->LDS feed
//   (same constant back-computed from m97) because the VMEM queue empties during ds_read+
//   barriers. Fix = never drain: stage(kt+2) issued mid-iter kt, awaited at top of iter kt+2
//   via s_waitcnt vmcnt(9) (the 9 newest = stage(kt+1) stay in flight). Raw s_barrier only --
//   __syncthreads() would force vmcnt(0) and defeat the pipeline (that was R1's failure).
// Ordering contract per iteration kt:
//   vmcnt(9)   -> own stage(kt) landed;  s_barrier -> ALL waves' stage(kt) visible
//   ds_read buf[kt&1] -> regs;  lgkmcnt(0) + s_barrier -> all waves done reading buf[kt&1]
//   issue stage(kt+2) into buf[kt&1]  (9 async loads; fly across the rest of kt and all of kt+1)
//   60 MFMAs
// No other VMEM inside the loop (epilogue loads are post-loop) so the vmcnt count is exact.
// Bank-conflict swizzle (R4, verified SQ_LDS_BANK_CONFLICT=0): slot q holds global chunk
// q ^ ((row>>1)&3); LDS dest linear; read offset uses the same XOR folded into aoff/boff.
template<bool IS_ZR>
__global__ __launch_bounds__(256, 2) void gemm_kernel(
    const __hip_bfloat16* __restrict__ Abuf,   // [rows][SA_] chunk-local
    const __hip_bfloat16* __restrict__ W,      // [Nout][SW_]
    const float* __restrict__ bw1, const float* __restrict__ bu1,
    const float* __restrict__ bw2, const float* __restrict__ bu2,
    const float* __restrict__ hcur,            // [rows][1024] fp32, chunk-local
    float* __restrict__ zbuf,                  // [rows][1024] fp32, chunk-local
    __hip_bfloat16* __restrict__ rhbase,       // = Abuf (rh at cols 6144/7168)
    float* __restrict__ hout,
    int mtiles) {
  __shared__ bf16x8 ldsA[2560];   // 40 KB: dbuf(2) x plane(2) x 160 m-rows x 4 chunks
  __shared__ bf16x8 ldsB[2048];   // 32 KB: dbuf(2) x plane(2) x 128 n-rows x 4 chunks

  const int ntiles = IS_ZR ? 16 : 8;           // 128-wide n tiles
  int mt, nt;
  if ((mtiles & 7) == 0) {
    const int flat = blockIdx.x;
    const int strip = mtiles >> 3;             // m-tiles per XCD
    const int xcd = flat & 7;
    const int loc = flat >> 3;                 // [0, strip*ntiles)
    mt = xcd * strip + loc / ntiles;
    nt = loc - (loc / ntiles) * ntiles;
  } else {
    mt = blockIdx.x / ntiles;
    nt = blockIdx.x - mt * ntiles;
  }
  const int m0 = mt * 160;
  const int n0 = nt * 128;

  const int tid  = threadIdx.x;
  const int lane = tid & 63;
  const int wave = tid >> 6;
  const int wm   = (wave & 1) * 80;
  const int wn   = (wave >> 1) * 64;
  const int l15  = lane & 15;
  const int l4   = lane >> 4;
  const int UBASE = IS_ZR ? 4096 : 6144;   // u-operand: h for ZR, r*h for H

  f32x4 acc[5][4];
  #pragma unroll
  for (int i = 0; i < 5; ++i)
    #pragma unroll
    for (int j = 0; j < 4; ++j) acc[i][j] = (f32x4){0.f, 0.f, 0.f, 0.f};

  // swizzled, loop-invariant operand read offsets (slot units of 16B)
  const int arow = wm + l15;
  const int brow = wn + l15;
  const int aoff = arow * 4 + (l4 ^ ((arow >> 1) & 3));
  const int boff = brow * 4 + (l4 ^ ((brow >> 1) & 3));

  // staging: 9 async 16B copies (A:5, B:4) for one K-chunk into buffer BUF.
  // global chunk pre-swizzled by q ^ ((row>>1)&3); LDS destination linear.
  #define STAGE_TILE(BUF, AHI, ALO, WHI, WLO) do {                                             \
      _Pragma("unroll")                                                                        \
      for (int i_ = 0; i_ < 5; ++i_) {            /* A: 1280 slots (2 pl x 160 x 4) */         \
        const int cidx = i_ * 256 + tid;                                                       \
        const int pl = cidx / 640;                                                             \
        const int rr = cidx - pl * 640;                                                        \
        const int q  = rr & 3;                                                                 \
        const int mm = rr >> 2;                                                                \
        const int qg = q ^ ((mm >> 1) & 3);                                                    \
        async_cp16(Abuf + (size_t)(m0 + mm) * SA_ + (pl ? (ALO) : (AHI)) + qg * 8,             \
                   &ldsA[(BUF) * 1280 + cidx]);                                                \
      }                                                                                        \
      _Pragma("unroll")                                                                        \
      for (int j_ = 0; j_ < 4; ++j_) {            /* B: 1024 slots (2 pl x 128 x 4) */         \
        const int cidx = j_ * 256 + tid;                                                       \
        const int pl = cidx >> 9;                                                              \
        const int q  = cidx & 3;                                                               \
        const int nn = (cidx >> 2) & 127;                                                      \
        const int qg = q ^ ((nn >> 1) & 3);                                                    \
        async_cp16(W + (size_t)(n0 + nn) * SW_ + (pl ? (WLO) : (WHI)) + qg * 8,                \
                   &ldsB[(BUF) * 1024 + cidx]);                                                \
      }                                                                                        \
    } while (0)

  // prologue: stage tiles 0 and 1 (18 loads in flight)
  int ahi, alo, whi, wlo;
  plane_offsets(0, UBASE, ahi, alo, whi, wlo);
  STAGE_TILE(0, ahi, alo, whi, wlo);
  plane_offsets(1, UBASE, ahi, alo, whi, wlo);
  STAGE_TILE(1, ahi, alo, whi, wlo);

  for (int kt = 0; kt < KT_; ++kt) {
    // tile-ready wait: own stage(kt) landed; keep stage(kt+1)'s 9 loads in flight.
    if (kt < KT_ - 1) { asm volatile("s_waitcnt vmcnt(9)" ::: "memory"); }
    else              { asm volatile("s_waitcnt vmcnt(0)" ::: "memory"); }
    __builtin_amdgcn_sched_barrier(0);
    __builtin_amdgcn_s_barrier();              // all waves' stage(kt) visible
    __builtin_amdgcn_sched_barrier(0);

    const int abase = (kt & 1) * 1280;
    const int bbase = (kt & 1) * 1024;
    bf16x8 af_h[5], af_l[5], bb_h[4], bb_l[4];
    #pragma unroll
    for (int mi = 0; mi < 5; ++mi) { af_h[mi] = ldsA[abase + aoff + mi * 64];
                                     af_l[mi] = ldsA[abase + 640 + aoff + mi * 64]; }
    #pragma unroll
    for (int ni = 0; ni < 4; ++ni) { bb_h[ni] = ldsB[bbase + boff + ni * 64];
                                     bb_l[ni] = ldsB[bbase + 512 + boff + ni * 64]; }
    asm volatile("s_waitcnt lgkmcnt(0)" ::: "memory");
    __builtin_amdgcn_sched_barrier(0);
    __builtin_amdgcn_s_barrier();              // all waves done reading buf[kt&1]
    __builtin_amdgcn_sched_barrier(0);

    if (kt + 2 < KT_) {                        // stage kt+2 into the buffer just vacated
      plane_offsets(kt + 2, UBASE, ahi, alo, whi, wlo);
      STAGE_TILE(kt & 1, ahi, alo, whi, wlo);
    }

    #pragma unroll
    for (int mi = 0; mi < 5; ++mi)             // seg0: a_hi * w_hi
      #pragma unroll
      for (int ni = 0; ni < 4; ++ni)
        acc[mi][ni] = __builtin_amdgcn_mfma_f32_16x16x32_bf16(af_h[mi], bb_h[ni], acc[mi][ni], 0, 0, 0);
    #pragma unroll
    for (int mi = 0; mi < 5; ++mi)             // seg1: a_lo * w_hi
      #pragma unroll
      for (int ni = 0; ni < 4; ++ni)
        acc[mi][ni] = __builtin_amdgcn_mfma_f32_16x16x32_bf16(af_l[mi], bb_h[ni], acc[mi][ni], 0, 0, 0);
    #pragma unroll
    for (int mi = 0; mi < 5; ++mi)             // seg2: a_hi * w_lo
      #pragma unroll
      for (int ni = 0; ni < 4; ++ni)
        acc[mi][ni] = __builtin_amdgcn_mfma_f32_16x16x32_bf16(af_h[mi], bb_l[ni], acc[mi][ni], 0, 0, 0);
  }
  #undef STAGE_TILE

  // epilogue: C/D layout col = lane&15, row = (lane>>4)*4 + reg
  #pragma unroll
  for (int mi = 0; mi < 5; ++mi) {
    #pragma unroll
    for (int p = 0; p < 4; ++p) {
      const int m = m0 + wm + mi * 16 + l4 * 4 + p;
      #pragma unroll
      for (int ni = 0; ni < 4; ++ni) {
        const int n = n0 + wn + ni * 16 + l15;
        float v = acc[mi][ni][p];
        if (IS_ZR) {
          if (n < 1024) {
            zbuf[(size_t)m * 1024 + n] = sigm_(v + bw1[n] + bu1[n]);
          } else {
            const int nn2 = n - 1024;
            float r = sigm_(v + bw2[nn2] + bu2[nn2]);
            float rh = r * hcur[(size_t)m * 1024 + nn2];
            __hip_bfloat16 hi, lo; split_bf16(rh, hi, lo);
            rhbase[(size_t)m * SA_ + 6144 + nn2] = hi;
            rhbase[(size_t)m * SA_ + 7168 + nn2] = lo;
          }
        } else {
          float hc = tanh_(v + bw1[n] + bu1[n]);
          float z  = zbuf[(size_t)m * 1024 + n];
          float ho = hcur[(size_t)m * 1024 + n];
          hout[(size_t)m * 1024 + n] = (1.0f - z) * ho + z * hc;
        }
      }
    }
  }
}

extern "C" void kernel_launch(void* const* d_in, const int* in_sizes, int n_in,
                              void* d_out, int out_size, void* d_ws, size_t ws_size,
                              hipStream_t stream) {
  const float* x    = (const float*)d_in[0];
  const float* inM  = (const float*)d_in[1];
  const float* outM = (const float*)d_in[2];
  const float* W1w  = (const float*)d_in[3];
  const float* b1w  = (const float*)d_in[4];
  const float* W1u  = (const float*)d_in[5];
  const float* b1u  = (const float*)d_in[6];
  const float* W2w  = (const float*)d_in[7];
  const float* b2w  = (const float*)d_in[8];
  const float* W2u  = (const float*)d_in[9];
  const float* b2u  = (const float*)d_in[10];
  const float* W3w  = (const float*)d_in[11];
  const float* b3w  = (const float*)d_in[12];
  const float* W3u  = (const float*)d_in[13];
  const float* b3u  = (const float*)d_in[14];
  float* hout = (float*)d_out;   // h lives in d_out across timesteps

  char* ws = (char*)d_ws;
  __hip_bfloat16* Wzr = (__hip_bfloat16*)ws;                 // 2048*6144*2 = 25,165,824 B
  __hip_bfloat16* Wh  = (__hip_bfloat16*)(ws + 25165824);    // 1024*6144*2 = 12,582,912 B
  const size_t fixed = 37748736;
  // per-batch-element chunk cost: Abuf 80*SA_*2 + zbuf 80*1024*4 = 1,638,400 B
  int Rb = 256;                                              // batch elems per chunk (mult of 8)
  while (Rb > 8 && fixed + (size_t)Rb * 1638400ull > ws_size) Rb -= 8;
  float* zbuf = (float*)(ws + fixed);                        // Rb*80*1024*4
  __hip_bfloat16* Abuf = (__hip_bfloat16*)(ws + fixed + (size_t)Rb * 327680ull);

  pack_weights<<<(3072 * 3072) / 256, 256, 0, stream>>>(
      W1w, W1u, W2w, W2u, W3w, W3u, Wzr, Wh);

  for (int t = 0; t < 3; ++t) {
    const float* hsrc = (t == 0) ? x : (const float*)hout;
    for (int b0 = 0; b0 < B_; b0 += Rb) {
      const int nb = (B_ - b0 < Rb) ? (B_ - b0) : Rb;
      const int rows = N_ * nb;                  // 80*nb, nb mult of 8 -> /160 integral
      const int mtiles = rows / 160;
      const float* hc = hsrc + (size_t)b0 * N_ * D_;
      prop_kernel<<<dim3(nb, D_ / 256), 256, 0, stream>>>(hc, inM, outM, Abuf);
      gemm_kernel<true><<<mtiles * 16, 256, 0, stream>>>(
          Abuf, Wzr, b1w, b1u, b2w, b2u, hc, zbuf, Abuf, nullptr, mtiles);
      gemm_kernel<false><<<mtiles * 8, 256, 0, stream>>>(
          Abuf, Wh, b3w, b3u, nullptr, nullptr, hc, zbuf, nullptr,
          hout + (size_t)b0 * N_ * D_, mtiles);
    }
  }
}